// Round 2
// baseline (221.372 us; speedup 1.0000x reference)
//
#include <hip/hip_runtime.h>

#define VOCAB 1000000
#define NUM_TABLES 10
#define OUT_SIZE 26
#define BUCKET_BITS 12
#define BPB 4096                // bins per bucket
#define NBUCKETS 245            // ceil(1e6/4096)
#define CHUNK 4096              // indices per scatter block
#define MAXSRC 1024             // max scatter blocks supported by fast path
#define GSTRIDE 256             // gs32 row stride per src (>= NBUCKETS)
#define NPB NBUCKETS            // partial blocks per series
#define NSERIES 30              // 10 tables x 3 dims
#define TSPLIT 5                // table-pairs per bucket
#define PTHREADS 512            // threads in bucket_pair_kernel

// ---------------- fast path ----------------

// Partition indices by bucket (idx>>12) into each block's PRIVATE dense region.
// No global atomics; pass-2 permutation staged in LDS, dumped coalesced.
__global__ void __launch_bounds__(256) scatter_kernel(
    const int* __restrict__ idx, int n,
    unsigned short* __restrict__ scat,   // [nsrc][CHUNK] u16 (bin within bucket)
    unsigned int* __restrict__ gs32)     // [src][GSTRIDE]: start | count<<16  (coalesced write)
{
    __shared__ unsigned int lcount[256];
    __shared__ unsigned int sc[256];
    __shared__ __align__(16) unsigned short stage[CHUNK];   // 8 KB
    const int tid = threadIdx.x;
    lcount[tid] = 0u;
    __syncthreads();

    const int4* idx4 = (const int4*)idx;
    const int n4 = n >> 2;
    const int base4 = blockIdx.x * (CHUNK / 4);
    int4 q[4];
    bool val[4];
    unsigned rank[16];
    unsigned bkt[16];
#pragma unroll
    for (int j = 0; j < 4; ++j) {
        int i4 = base4 + j * 256 + tid;
        val[j] = (i4 < n4);
        if (val[j]) q[j] = idx4[i4];
    }
    // pass 1: per-element rank within (block, bucket)
#pragma unroll
    for (int j = 0; j < 4; ++j) {
        if (val[j]) {
            unsigned v[4] = {(unsigned)q[j].x, (unsigned)q[j].y, (unsigned)q[j].z, (unsigned)q[j].w};
#pragma unroll
            for (int e = 0; e < 4; ++e) {
                bkt[j * 4 + e] = v[e] >> BUCKET_BITS;
                rank[j * 4 + e] = atomicAdd(&lcount[bkt[j * 4 + e]], 1u);
            }
        }
    }
    // tail (n%4): last block, thread 0 (dead code for n=4M)
    unsigned trank[3], tbkt[3];
    int tcnt = 0;
    if (blockIdx.x == gridDim.x - 1 && tid == 0) {
        for (int i = n4 * 4; i < n; ++i) {
            unsigned u = (unsigned)idx[i];
            tbkt[tcnt] = u >> BUCKET_BITS;
            trank[tcnt] = atomicAdd(&lcount[tbkt[tcnt]], 1u);
            ++tcnt;
        }
    }
    __syncthreads();
    // inclusive scan over 245 bucket counts (padded to 256)
    unsigned cnt = (tid < NBUCKETS) ? lcount[tid] : 0u;
    sc[tid] = cnt;
    __syncthreads();
#pragma unroll
    for (int off = 1; off < 256; off <<= 1) {
        unsigned v = sc[tid];
        unsigned a = (tid >= off) ? sc[tid - off] : 0u;
        __syncthreads();
        sc[tid] = v + a;
        __syncthreads();
    }
    unsigned excl = sc[tid] - cnt;
    if (tid < NBUCKETS) gs32[(size_t)blockIdx.x * GSTRIDE + tid] = excl | (cnt << 16);
    lcount[tid] = excl;   // reuse as per-bucket base
    __syncthreads();
    // pass 2: scatter into LDS stage (unique positions, no atomics)
#pragma unroll
    for (int j = 0; j < 4; ++j) {
        if (val[j]) {
            unsigned v[4] = {(unsigned)q[j].x, (unsigned)q[j].y, (unsigned)q[j].z, (unsigned)q[j].w};
#pragma unroll
            for (int e = 0; e < 4; ++e) {
                unsigned k = j * 4 + e;
                stage[lcount[bkt[k]] + rank[k]] = (unsigned short)(v[e] & (BPB - 1));
            }
        }
    }
    if (blockIdx.x == gridDim.x - 1 && tid == 0) {
        for (int i = 0; i < tcnt; ++i) {
            unsigned u = (unsigned)idx[n4 * 4 + i];
            stage[lcount[tbkt[i]] + trank[i]] = (unsigned short)(u & (BPB - 1));
        }
    }
    __syncthreads();
    // coalesced dump: 4096 u16 = 512 uint4
    uint4* dst = (uint4*)(scat + (size_t)blockIdx.x * CHUNK);
    const uint4* src = (const uint4*)stage;
#pragma unroll
    for (int j = 0; j < 2; ++j) dst[j * 256 + tid] = src[j * 256 + tid];
}

__device__ inline float wave_reduce(float v) {
#pragma unroll
    for (int o = 32; o > 0; o >>= 1) v += __shfl_down(v, o, 64);
    return v;
}

// FUSED, table-pair split: grid = NBUCKETS * TSPLIT blocks of 512 threads.
// Block (b, tp): builds bucket b's 4096-bin hist in LDS (gather duplicated
// across the 5 tp-blocks; scat is L3-resident), then reduces ONLY tables
// {2tp, 2tp+1} -> 6 register accumulators (no spill; R1's 30-acc version
// spilled at VGPR_Count=40 and ran 69.6us latency-bound).
// 8-wave blocks, 4 co-resident/CU -> gather of one block overlaps W-stream
// of another.
__global__ void __launch_bounds__(PTHREADS) bucket_pair_kernel(
    const unsigned short* __restrict__ scat,
    const unsigned int* __restrict__ gs32, int nsrc,
    const float* __restrict__ W,
    float* __restrict__ partials)        // [NSERIES][NPB]
{
    __shared__ __align__(16) unsigned int h[BPB];   // 16 KB
    __shared__ float sm[8][6];
    const int b = blockIdx.x / TSPLIT;
    const int tp = blockIdx.x % TSPLIT;
    const int tid = threadIdx.x;
#pragma unroll
    for (int i = 0; i < BPB / 4 / PTHREADS; ++i)
        ((uint4*)h)[i * PTHREADS + tid] = make_uint4(0u, 0u, 0u, 0u);
    __syncthreads();
    // gather phase: strided over source blocks
    for (int s = tid; s < nsrc; s += PTHREADS) {
        unsigned g32 = gs32[(size_t)s * GSTRIDE + b];
        unsigned st = g32 & 0xffffu, c = g32 >> 16;
        const unsigned short* p = scat + (size_t)s * CHUNK + st;
        unsigned k = 0;
        for (; k + 4 <= c; k += 4) {
            unsigned short a0 = p[k], a1 = p[k + 1], a2 = p[k + 2], a3 = p[k + 3];
            atomicAdd(&h[a0], 1u);
            atomicAdd(&h[a1], 1u);
            atomicAdd(&h[a2], 1u);
            atomicAdd(&h[a3], 1u);
        }
        for (; k < c; ++k) atomicAdd(&h[p[k]], 1u);
    }
    __syncthreads();

    // reduce phase: 2 tables, 2 row-groups per thread, 6 accumulators
    const int nbg = min(BPB, VOCAB - b * BPB) >> 2;   // 1024 (144 for b=244)
    float acc[2][3];
#pragma unroll
    for (int i = 0; i < 2; ++i) { acc[i][0] = 0.f; acc[i][1] = 0.f; acc[i][2] = 0.f; }
#pragma unroll
    for (int rep = 0; rep < 2; ++rep) {
        const int gg = rep * PTHREADS + tid;
        if (gg < nbg) {
            uint4 c4 = ((const uint4*)h)[gg];
            float c0 = (float)c4.x, c1 = (float)c4.y, c2 = (float)c4.z, c3 = (float)c4.w;
            const int g = b * (BPB / 4) + gg;         // global 4-row group index
#pragma unroll
            for (int i = 0; i < 2; ++i) {
                const int t = tp * 2 + i;
                const float4* __restrict__ W4 = (const float4*)(W + (size_t)t * VOCAB * 3);
                float4 w0 = W4[3 * g + 0];
                float4 w1 = W4[3 * g + 1];
                float4 w2 = W4[3 * g + 2];
                acc[i][0] += c0 * w0.x + c1 * w0.w + c2 * w1.z + c3 * w2.y;
                acc[i][1] += c0 * w0.y + c1 * w1.x + c2 * w1.w + c3 * w2.z;
                acc[i][2] += c0 * w0.z + c1 * w1.y + c2 * w2.x + c3 * w2.w;
            }
        }
    }
    // block reduction: 6 series
    const int wave = tid >> 6, lane = tid & 63;
#pragma unroll
    for (int i = 0; i < 2; ++i) {
#pragma unroll
        for (int d = 0; d < 3; ++d) {
            float v = wave_reduce(acc[i][d]);
            if (lane == 0) sm[wave][i * 3 + d] = v;
        }
    }
    __syncthreads();
    if (tid < 6) {
        float v = 0.f;
#pragma unroll
        for (int w = 0; w < 8; ++w) v += sm[w][tid];
        const int srs = (tp * 2 + tid / 3) * 3 + (tid % 3);
        partials[(size_t)srs * NPB + b] = v;
    }
}

__global__ void __launch_bounds__(1024) final_kernel(const float* __restrict__ partials,
                                                     float* __restrict__ out) {
    __shared__ float ts[32];
    const int tid = threadIdx.x;
    const int srs = tid >> 5;      // series 0..31 (use <30): s = t*3+d
    const int j = tid & 31;
    float v = 0.f;
    if (srs < NSERIES) {
        const float* p = partials + (size_t)srs * NPB;
#pragma unroll
        for (int k = 0; k < 8; ++k) {
            int i = k * 32 + j;
            if (i < NPB) v += p[i];
        }
    }
#pragma unroll
    for (int off = 16; off > 0; off >>= 1) v += __shfl_down(v, off);
    if (j == 0 && srs < NSERIES) ts[srs] = v;
    __syncthreads();
    if (tid < OUT_SIZE) {
        float r;
        if (tid < 15) r = ts[tid];
        else if (tid == 15) r = ts[15] + ts[16] + ts[17];
        else if (tid == 16) r = ts[18] + ts[19] + ts[20];
        else r = ts[tid + 4];
        out[tid] = r;
    }
}

// ---------------- fallback path (R1, proven) ----------------

__global__ void zero_kernel_fb(unsigned int* __restrict__ hist, float* __restrict__ out) {
    int i = blockIdx.x * blockDim.x + threadIdx.x;
    int n4 = VOCAB / 4;
    if (i < n4) ((uint4*)hist)[i] = make_uint4(0u, 0u, 0u, 0u);
    if (i < OUT_SIZE) out[i] = 0.0f;
}

__global__ void hist_kernel_fb(const int* __restrict__ idx, unsigned int* __restrict__ hist, int n) {
    int i = blockIdx.x * blockDim.x + threadIdx.x;
    int i4 = i * 4;
    if (i4 + 3 < n) {
        int4 v = ((const int4*)idx)[i];
        atomicAdd(&hist[v.x], 1u);
        atomicAdd(&hist[v.y], 1u);
        atomicAdd(&hist[v.z], 1u);
        atomicAdd(&hist[v.w], 1u);
    } else {
        for (int j = i4; j < n; ++j) atomicAdd(&hist[idx[j]], 1u);
    }
}

#define RTHREADS 256

__global__ void __launch_bounds__(RTHREADS) reduce_kernel_fb(const float* __restrict__ W,
                                                             const unsigned int* __restrict__ hist,
                                                             float* __restrict__ out) {
    const int t = blockIdx.x / 64;
    const int b = blockIdx.x % 64;
    const float4* __restrict__ W4 = (const float4*)(W + (size_t)t * VOCAB * 3);
    const uint4* __restrict__ h4 = (const uint4*)hist;
    const int ngroups = VOCAB / 4;
    float a0 = 0.f, a1 = 0.f, a2 = 0.f;
    const int stride = 64 * RTHREADS;
    for (int g = b * RTHREADS + (int)threadIdx.x; g < ngroups; g += stride) {
        uint4 c4 = h4[g];
        float4 w0 = W4[3 * g + 0];
        float4 w1 = W4[3 * g + 1];
        float4 w2 = W4[3 * g + 2];
        float c0 = (float)c4.x, c1 = (float)c4.y, c2 = (float)c4.z, c3 = (float)c4.w;
        a0 += c0 * w0.x + c1 * w0.w + c2 * w1.z + c3 * w2.y;
        a1 += c0 * w0.y + c1 * w1.x + c2 * w1.w + c3 * w2.z;
        a2 += c0 * w0.z + c1 * w1.y + c2 * w2.x + c3 * w2.w;
    }
    a0 = wave_reduce(a0);
    a1 = wave_reduce(a1);
    a2 = wave_reduce(a2);
    __shared__ float s[3][4];
    int wave = threadIdx.x >> 6;
    int lane = threadIdx.x & 63;
    if (lane == 0) { s[0][wave] = a0; s[1][wave] = a1; s[2][wave] = a2; }
    __syncthreads();
    if (threadIdx.x == 0) {
        float r0 = s[0][0] + s[0][1] + s[0][2] + s[0][3];
        float r1 = s[1][0] + s[1][1] + s[1][2] + s[1][3];
        float r2 = s[2][0] + s[2][1] + s[2][2] + s[2][3];
        if (t == 5) atomicAdd(&out[15], r0 + r1 + r2);
        else if (t == 6) atomicAdd(&out[16], r0 + r1 + r2);
        else {
            int base = (t < 5) ? t * 3 : 17 + (t - 7) * 3;
            atomicAdd(&out[base + 0], r0);
            atomicAdd(&out[base + 1], r1);
            atomicAdd(&out[base + 2], r2);
        }
    }
}

// ---------------- launch ----------------

extern "C" void kernel_launch(void* const* d_in, const int* in_sizes, int n_in,
                              void* d_out, int out_size, void* d_ws, size_t ws_size,
                              hipStream_t stream) {
    const int* eb_input = (const int*)d_in[0];
    // d_in[1] (eb_offset) irrelevant: sum over all bags == sum over all indices.
    const float* W = (const float*)d_in[2];
    float* out = (float*)d_out;
    int n_idx = in_sizes[0];

    const int nsrc = (n_idx + CHUNK - 1) / CHUNK;
    const size_t scat_bytes = (size_t)MAXSRC * CHUNK * 2;        // 8,388,608
    const size_t gs_off = scat_bytes;
    const size_t gs_bytes = (size_t)MAXSRC * GSTRIDE * 4;        // 1,048,576
    const size_t part_off = (gs_off + gs_bytes + 255) & ~(size_t)255;
    const size_t need = part_off + (size_t)NSERIES * NPB * 4;    // ~9.5 MB

    if (nsrc <= MAXSRC && ws_size >= need) {
        unsigned short* scat = (unsigned short*)d_ws;
        unsigned int* gs32 = (unsigned int*)((char*)d_ws + gs_off);
        float* partials = (float*)((char*)d_ws + part_off);

        scatter_kernel<<<nsrc, 256, 0, stream>>>(eb_input, n_idx, scat, gs32);
        bucket_pair_kernel<<<NBUCKETS * TSPLIT, PTHREADS, 0, stream>>>(scat, gs32, nsrc, W, partials);
        final_kernel<<<1, 1024, 0, stream>>>(partials, out);
    } else {
        unsigned int* hist = (unsigned int*)d_ws;
        int zblocks = (VOCAB / 4 + 255) / 256;
        zero_kernel_fb<<<zblocks, 256, 0, stream>>>(hist, out);
        int hthreads = (n_idx + 3) / 4;
        int hblocks = (hthreads + 255) / 256;
        hist_kernel_fb<<<hblocks, 256, 0, stream>>>(eb_input, hist, n_idx);
        reduce_kernel_fb<<<NUM_TABLES * 64, RTHREADS, 0, stream>>>(W, hist, out);
    }
}

// Round 4
// 207.726 us; speedup vs baseline: 1.0657x; 1.0657x over previous
//
#include <hip/hip_runtime.h>

#define VOCAB 1000000
#define NUM_TABLES 10
#define OUT_SIZE 26
#define BUCKET_BITS 12
#define BPB 4096                // bins per bucket
#define NBUCKETS 245            // ceil(1e6/4096)
#define CHUNK 16384             // indices per scatter block (big => ~67-elem segments)
#define MAXSRC 256              // max scatter blocks supported by fast path
#define GSTRIDE 256             // gs32 row stride per src (>= NBUCKETS)
#define RBLOCKS_PER_TABLE 256
#define NRBLK (NUM_TABLES * RBLOCKS_PER_TABLE)   // 2560
#define RTHREADS 256

// ---------------- fast path ----------------

// Partition 16384 indices/block by bucket (idx>>12) into the block's PRIVATE
// dense region. No global atomics; pass-2 permutation staged in LDS, dumped
// coalesced. 1024 threads, 16 elements each.
__global__ void __launch_bounds__(1024) scatter_kernel(
    const int* __restrict__ idx, int n,
    unsigned short* __restrict__ scat,   // [nsrc][CHUNK] u16 (bin within bucket)
    unsigned int* __restrict__ gs32)     // [src][GSTRIDE]: start | count<<16 (coalesced write)
{
    __shared__ unsigned int lcount[256];
    __shared__ unsigned int sc[256];
    __shared__ __align__(16) unsigned short stage[CHUNK];   // 32 KB
    const int tid = threadIdx.x;
    if (tid < 256) lcount[tid] = 0u;
    __syncthreads();

    const int4* idx4 = (const int4*)idx;
    const int n4 = n >> 2;
    const int base4 = blockIdx.x * (CHUNK / 4);
    int4 q[4];
    bool val[4];
    unsigned rank[16];
    unsigned bkt[16];
#pragma unroll
    for (int j = 0; j < 4; ++j) {
        int i4 = base4 + j * 1024 + tid;
        val[j] = (i4 < n4);
        if (val[j]) q[j] = idx4[i4];
    }
    // pass 1: per-element rank within (block, bucket)
#pragma unroll
    for (int j = 0; j < 4; ++j) {
        if (val[j]) {
            unsigned v[4] = {(unsigned)q[j].x, (unsigned)q[j].y, (unsigned)q[j].z, (unsigned)q[j].w};
#pragma unroll
            for (int e = 0; e < 4; ++e) {
                bkt[j * 4 + e] = v[e] >> BUCKET_BITS;
                rank[j * 4 + e] = atomicAdd(&lcount[bkt[j * 4 + e]], 1u);
            }
        }
    }
    // tail (n%4): last block, thread 0 (dead code for n=4M)
    unsigned trank[3], tbkt[3];
    int tcnt = 0;
    if (blockIdx.x == gridDim.x - 1 && tid == 0) {
        for (int i = n4 * 4; i < n; ++i) {
            unsigned u = (unsigned)idx[i];
            tbkt[tcnt] = u >> BUCKET_BITS;
            trank[tcnt] = atomicAdd(&lcount[tbkt[tcnt]], 1u);
            ++tcnt;
        }
    }
    __syncthreads();
    // inclusive scan over 245 bucket counts (first 256 threads; padded to 256)
    unsigned cnt = 0;
    if (tid < 256) {
        cnt = (tid < NBUCKETS) ? lcount[tid] : 0u;
        sc[tid] = cnt;
    }
    __syncthreads();
#pragma unroll
    for (int off = 1; off < 256; off <<= 1) {
        unsigned v = 0, a = 0;
        if (tid < 256) {
            v = sc[tid];
            if (tid >= off) a = sc[tid - off];
        }
        __syncthreads();
        if (tid < 256) sc[tid] = v + a;
        __syncthreads();
    }
    if (tid < 256) {
        unsigned excl = sc[tid] - cnt;
        if (tid < NBUCKETS) gs32[(size_t)blockIdx.x * GSTRIDE + tid] = excl | (cnt << 16);
        lcount[tid] = excl;   // reuse as per-bucket base
    }
    __syncthreads();
    // pass 2: scatter into LDS stage (unique positions, no atomics)
#pragma unroll
    for (int j = 0; j < 4; ++j) {
        if (val[j]) {
            unsigned v[4] = {(unsigned)q[j].x, (unsigned)q[j].y, (unsigned)q[j].z, (unsigned)q[j].w};
#pragma unroll
            for (int e = 0; e < 4; ++e) {
                unsigned k = j * 4 + e;
                stage[lcount[bkt[k]] + rank[k]] = (unsigned short)(v[e] & (BPB - 1));
            }
        }
    }
    if (blockIdx.x == gridDim.x - 1 && tid == 0) {
        for (int i = 0; i < tcnt; ++i) {
            unsigned u = (unsigned)idx[n4 * 4 + i];
            stage[lcount[tbkt[i]] + trank[i]] = (unsigned short)(u & (BPB - 1));
        }
    }
    __syncthreads();
    // coalesced dump: 16384 u16 = 2048 uint4
    uint4* dst = (uint4*)(scat + (size_t)blockIdx.x * CHUNK);
    const uint4* src = (const uint4*)stage;
#pragma unroll
    for (int j = 0; j < 2; ++j) dst[j * 1024 + tid] = src[j * 1024 + tid];
}

// One block per bucket: build 4096-bin hist in LDS, write coalesced.
// WAVE-COOPERATIVE gather: each wave owns one source chunk at a time; lanes
// stride the contiguous ~67-elem segment => coalesced 128B wave-loads.
// (R0-R2's per-THREAD segment walk was 1 cache line per u16 load — the
// hidden request-rate bottleneck: VALUBusy 6%, HBM 17%, all pipes idle.)
__global__ void __launch_bounds__(1024) bucket_hist_kernel(
    const unsigned short* __restrict__ scat,
    const unsigned int* __restrict__ gs32, int nsrc,
    unsigned int* __restrict__ hist)
{
    __shared__ __align__(16) unsigned int h[BPB];   // 16 KB
    const int b = blockIdx.x;
    const int tid = threadIdx.x;
    const int wave = tid >> 6, lane = tid & 63;
    ((uint4*)h)[tid] = make_uint4(0u, 0u, 0u, 0u);   // 1024 * uint4 = 4096
    __syncthreads();
    for (int s = wave; s < nsrc; s += 16) {
        unsigned g32 = gs32[(size_t)s * GSTRIDE + b];   // broadcast (same addr per wave)
        unsigned st = g32 & 0xffffu, c = g32 >> 16;
        const unsigned short* p = scat + (size_t)s * CHUNK + st;
        for (unsigned k = lane; k < c; k += 64)
            atomicAdd(&h[p[k]], 1u);
    }
    __syncthreads();
    int nb4 = min(BPB, VOCAB - b * BPB) >> 2;   // 1024 (144 for b=244)
    uint4* dst = (uint4*)(hist + (size_t)b * BPB);
    const uint4* src = (const uint4*)h;
    if (tid < nb4) dst[tid] = src[tid];
}

__device__ inline float wave_reduce(float v) {
#pragma unroll
    for (int o = 32; o > 0; o >>= 1) v += __shfl_down(v, o, 64);
    return v;
}

// Wide streaming reduce: hist + W -> per-block partials (no atomics).
// (R0's proven kernel: 3 accumulators, no spill, clean float4 stream.)
__global__ void __launch_bounds__(RTHREADS) reduce_kernel(const float* __restrict__ W,
                                                          const unsigned int* __restrict__ hist,
                                                          float* __restrict__ partials) {
    const int t = blockIdx.x / RBLOCKS_PER_TABLE;
    const int b = blockIdx.x % RBLOCKS_PER_TABLE;
    const float4* __restrict__ W4 = (const float4*)(W + (size_t)t * VOCAB * 3);
    const uint4* __restrict__ h4 = (const uint4*)hist;
    const int ngroups = VOCAB / 4;  // 250000
    float a0 = 0.f, a1 = 0.f, a2 = 0.f;
    const int stride = RBLOCKS_PER_TABLE * RTHREADS;
    for (int g = b * RTHREADS + (int)threadIdx.x; g < ngroups; g += stride) {
        uint4 c4 = h4[g];
        float4 w0 = W4[3 * g + 0];
        float4 w1 = W4[3 * g + 1];
        float4 w2 = W4[3 * g + 2];
        float c0 = (float)c4.x, c1 = (float)c4.y, c2 = (float)c4.z, c3 = (float)c4.w;
        a0 += c0 * w0.x + c1 * w0.w + c2 * w1.z + c3 * w2.y;
        a1 += c0 * w0.y + c1 * w1.x + c2 * w1.w + c3 * w2.z;
        a2 += c0 * w0.z + c1 * w1.y + c2 * w2.x + c3 * w2.w;
    }
    a0 = wave_reduce(a0);
    a1 = wave_reduce(a1);
    a2 = wave_reduce(a2);
    __shared__ float s[3][4];
    int wave = threadIdx.x >> 6;
    int lane = threadIdx.x & 63;
    if (lane == 0) { s[0][wave] = a0; s[1][wave] = a1; s[2][wave] = a2; }
    __syncthreads();
    if (threadIdx.x == 0) {
        partials[0 * NRBLK + blockIdx.x] = s[0][0] + s[0][1] + s[0][2] + s[0][3];
        partials[1 * NRBLK + blockIdx.x] = s[1][0] + s[1][1] + s[1][2] + s[1][3];
        partials[2 * NRBLK + blockIdx.x] = s[2][0] + s[2][1] + s[2][2] + s[2][3];
    }
}

__global__ void __launch_bounds__(1024) final_kernel(const float* __restrict__ partials,
                                                     float* __restrict__ out) {
    __shared__ float ts[32];
    const int tid = threadIdx.x;
    const int srs = tid >> 5;      // series 0..31 (use <30): s = t*3+d
    const int j = tid & 31;
    float v = 0.f;
    if (srs < 30) {
        const int t = srs / 3, d = srs % 3;
        const float* p = partials + (size_t)d * NRBLK + t * RBLOCKS_PER_TABLE;
#pragma unroll
        for (int k = 0; k < RBLOCKS_PER_TABLE / 32; ++k) v += p[k * 32 + j];
    }
#pragma unroll
    for (int off = 16; off > 0; off >>= 1) v += __shfl_down(v, off);
    if (j == 0 && srs < 30) ts[srs] = v;
    __syncthreads();
    if (tid < OUT_SIZE) {
        float r;
        if (tid < 15) r = ts[tid];
        else if (tid == 15) r = ts[15] + ts[16] + ts[17];
        else if (tid == 16) r = ts[18] + ts[19] + ts[20];
        else r = ts[tid + 4];
        out[tid] = r;
    }
}

// ---------------- fallback path (proven) ----------------

__global__ void zero_kernel_fb(unsigned int* __restrict__ hist, float* __restrict__ out) {
    int i = blockIdx.x * blockDim.x + threadIdx.x;
    int n4 = VOCAB / 4;
    if (i < n4) ((uint4*)hist)[i] = make_uint4(0u, 0u, 0u, 0u);
    if (i < OUT_SIZE) out[i] = 0.0f;
}

__global__ void hist_kernel_fb(const int* __restrict__ idx, unsigned int* __restrict__ hist, int n) {
    int i = blockIdx.x * blockDim.x + threadIdx.x;
    int i4 = i * 4;
    if (i4 + 3 < n) {
        int4 v = ((const int4*)idx)[i];
        atomicAdd(&hist[v.x], 1u);
        atomicAdd(&hist[v.y], 1u);
        atomicAdd(&hist[v.z], 1u);
        atomicAdd(&hist[v.w], 1u);
    } else {
        for (int j = i4; j < n; ++j) atomicAdd(&hist[idx[j]], 1u);
    }
}

__global__ void __launch_bounds__(RTHREADS) reduce_kernel_fb(const float* __restrict__ W,
                                                             const unsigned int* __restrict__ hist,
                                                             float* __restrict__ out) {
    const int t = blockIdx.x / 64;
    const int b = blockIdx.x % 64;
    const float4* __restrict__ W4 = (const float4*)(W + (size_t)t * VOCAB * 3);
    const uint4* __restrict__ h4 = (const uint4*)hist;
    const int ngroups = VOCAB / 4;
    float a0 = 0.f, a1 = 0.f, a2 = 0.f;
    const int stride = 64 * RTHREADS;
    for (int g = b * RTHREADS + (int)threadIdx.x; g < ngroups; g += stride) {
        uint4 c4 = h4[g];
        float4 w0 = W4[3 * g + 0];
        float4 w1 = W4[3 * g + 1];
        float4 w2 = W4[3 * g + 2];
        float c0 = (float)c4.x, c1 = (float)c4.y, c2 = (float)c4.z, c3 = (float)c4.w;
        a0 += c0 * w0.x + c1 * w0.w + c2 * w1.z + c3 * w2.y;
        a1 += c0 * w0.y + c1 * w1.x + c2 * w1.w + c3 * w2.z;
        a2 += c0 * w0.z + c1 * w1.y + c2 * w2.x + c3 * w2.w;
    }
    a0 = wave_reduce(a0);
    a1 = wave_reduce(a1);
    a2 = wave_reduce(a2);
    __shared__ float s[3][4];
    int wave = threadIdx.x >> 6;
    int lane = threadIdx.x & 63;
    if (lane == 0) { s[0][wave] = a0; s[1][wave] = a1; s[2][wave] = a2; }
    __syncthreads();
    if (threadIdx.x == 0) {
        float r0 = s[0][0] + s[0][1] + s[0][2] + s[0][3];
        float r1 = s[1][0] + s[1][1] + s[1][2] + s[1][3];
        float r2 = s[2][0] + s[2][1] + s[2][2] + s[2][3];
        if (t == 5) atomicAdd(&out[15], r0 + r1 + r2);
        else if (t == 6) atomicAdd(&out[16], r0 + r1 + r2);
        else {
            int base = (t < 5) ? t * 3 : 17 + (t - 7) * 3;
            atomicAdd(&out[base + 0], r0);
            atomicAdd(&out[base + 1], r1);
            atomicAdd(&out[base + 2], r2);
        }
    }
}

// ---------------- launch ----------------

extern "C" void kernel_launch(void* const* d_in, const int* in_sizes, int n_in,
                              void* d_out, int out_size, void* d_ws, size_t ws_size,
                              hipStream_t stream) {
    const int* eb_input = (const int*)d_in[0];
    // d_in[1] (eb_offset) irrelevant: sum over all bags == sum over all indices.
    const float* W = (const float*)d_in[2];
    float* out = (float*)d_out;
    int n_idx = in_sizes[0];

    const int nsrc = (n_idx + CHUNK - 1) / CHUNK;
    const size_t scat_bytes = (size_t)MAXSRC * CHUNK * 2;        // 8,388,608
    const size_t gs_off = scat_bytes;
    const size_t gs_bytes = (size_t)MAXSRC * GSTRIDE * 4;        // 262,144
    const size_t hist_off = gs_off + gs_bytes;
    const size_t hist_bytes = (size_t)VOCAB * 4;                 // 4,000,000
    const size_t part_off = (hist_off + hist_bytes + 255) & ~(size_t)255;
    const size_t need = part_off + (size_t)3 * NRBLK * 4;        // ~12.7 MB

    if (nsrc <= MAXSRC && ws_size >= need) {
        unsigned short* scat = (unsigned short*)d_ws;
        unsigned int* gs32 = (unsigned int*)((char*)d_ws + gs_off);
        unsigned int* hist = (unsigned int*)((char*)d_ws + hist_off);
        float* partials = (float*)((char*)d_ws + part_off);

        scatter_kernel<<<nsrc, 1024, 0, stream>>>(eb_input, n_idx, scat, gs32);
        bucket_hist_kernel<<<NBUCKETS, 1024, 0, stream>>>(scat, gs32, nsrc, hist);
        reduce_kernel<<<NRBLK, RTHREADS, 0, stream>>>(W, hist, partials);
        final_kernel<<<1, 1024, 0, stream>>>(partials, out);
    } else {
        unsigned int* hist = (unsigned int*)d_ws;
        int zblocks = (VOCAB / 4 + 255) / 256;
        zero_kernel_fb<<<zblocks, 256, 0, stream>>>(hist, out);
        int hthreads = (n_idx + 3) / 4;
        int hblocks = (hthreads + 255) / 256;
        hist_kernel_fb<<<hblocks, 256, 0, stream>>>(eb_input, hist, n_idx);
        reduce_kernel_fb<<<NUM_TABLES * 64, RTHREADS, 0, stream>>>(W, hist, out);
    }
}